// Round 1
// 345.404 us; speedup vs baseline: 1.2327x; 1.2327x over previous
//
#include <hip/hip_runtime.h>

// GRU4Rec fused, round 6: MFMA rewrite.
//
// r1-r5 lesson: the scan is matvec-shaped VALU work (192 fma_mix + 64
// readlane per step per seq) -> MfmaUtil 0, VALUBusy 73%, 274us, with a
// 64us pure-VALU floor. This round moves gh = W_hh @ h onto the matrix
// pipe by batching 16 sequences per wave:
//   D[192 gates x 16 seqs] = sum_k A(W_hh)[192x64] * B(h)[64x16]
// as 12 tiles x 2 K-slices of v_mfma_f32_16x16x32_f16.
// Layouts (guide, HW-verified): D col=lane&15 (seq), row=4*(lane>>4)+reg;
// A/B frags: 8 contiguous k per lane, k = 8*(lane>>4)+j.
// Per step, h_new (D layout) -> B fragment via a single-wave 2.5KB LDS
// transpose (4x ds_write_b64 + 2x ds_read_b128, 160B row stride = bank-
// sweep floor both directions, no barrier: 1 wave, in-order LDS pipe).
// h state carried in fp32; f16 (RNE) only as MFMA operands.
// P is precomputed in PLAIN gate order [r|z|n] by an MFMA proj kernel.
// Sort kernel deleted: 256 waves on 256 CUs -> makespan = global max L
// (~200 steps) with or without sorting.
//
// Shapes: B=4096, T=200, H=64, V=100000. Output fp32.

#define T_SEQ 200
#define HD 64
#define VOCAB 100000
#define PROW 192  // halves per P row, plain gate order [r|z|n]
#define TPW 5     // 16-row vocab tiles per proj wave (6250/5 = 1250 blocks)

typedef float v4f __attribute__((ext_vector_type(4)));
typedef float v8f __attribute__((ext_vector_type(8)));
typedef _Float16 v8h __attribute__((ext_vector_type(8)));
typedef _Float16 v4h __attribute__((ext_vector_type(4)));
typedef _Float16 h2 __attribute__((ext_vector_type(2)));
typedef unsigned v2u __attribute__((ext_vector_type(2)));

__device__ __forceinline__ float fsigmoid(float x) {
  float e = __builtin_amdgcn_exp2f(x * -1.442695040888963f);
  return __builtin_amdgcn_rcpf(1.0f + e);
}
__device__ __forceinline__ float ftanh(float x) {
  float e = __builtin_amdgcn_exp2f(x * -2.885390081777927f);
  return fmaf(2.0f, __builtin_amdgcn_rcpf(1.0f + e), -1.0f);
}
__device__ __forceinline__ float hlo(unsigned u) {
  h2 h = __builtin_bit_cast(h2, u);
  return (float)h[0];
}
__device__ __forceinline__ float hhi(unsigned u) {
  h2 h = __builtin_bit_cast(h2, u);
  return (float)h[1];
}
__device__ __forceinline__ unsigned pack_rne(float a, float b) {
  h2 w;
  w[0] = (_Float16)a;
  w[1] = (_Float16)b;
  return __builtin_bit_cast(unsigned, w);
}

// A-fragment of one [16 x 64] f32 row-major weight block (tile tau of 12,
// K-slice kappa of 2) for v_mfma_f32_16x16x32_f16.
// Lane l holds W[16*tau + (l&15)][32*kappa + 8*(l>>4) + j], j=0..7. RNE cvt.
__device__ __forceinline__ v8h load_wfrag(const float* __restrict__ W,
                                          int tau, int kappa, int m, int p) {
  const float* src = W + (size_t)(tau * 16 + m) * HD + kappa * 32 + p * 8;
  v8f f = *reinterpret_cast<const v8f*>(src);
  return __builtin_convertvector(f, v8h);
}

// ------------------------------------------------ phase 1: P = emb @ W_ih^T
// D[g][v]: lane holds vocab row v0+(lane&15), gates g = 16t+4p+q.
// Stores plain-order f16 rows: P[v][g], 8B per (tile,lane) store.
__global__ __launch_bounds__(64) void gru_proj_mfma(
    const float* __restrict__ emb, const float* __restrict__ W_ih,
    _Float16* __restrict__ P16) {
  const int l = threadIdx.x;
  const int m = l & 15;
  const int p = l >> 4;

  v8h A[12][2];
#pragma unroll
  for (int tt = 0; tt < 12; ++tt) {
    A[tt][0] = load_wfrag(W_ih, tt, 0, m, p);
    A[tt][1] = load_wfrag(W_ih, tt, 1, m, p);
  }
  const v4f zz = {0.f, 0.f, 0.f, 0.f};

#pragma unroll 1
  for (int it = 0; it < TPW; ++it) {
    const int tile = blockIdx.x * TPW + it;
    if (tile * 16 >= VOCAB) break;
    const int v = tile * 16 + m;
    const float* erow = emb + (size_t)v * HD + p * 8;
    v8h B0 = __builtin_convertvector(*reinterpret_cast<const v8f*>(erow), v8h);
    v8h B1 = __builtin_convertvector(*reinterpret_cast<const v8f*>(erow + 32), v8h);
    _Float16* orow = P16 + (size_t)v * PROW + p * 4;
#pragma unroll
    for (int tt = 0; tt < 12; ++tt) {
      v4f acc = __builtin_amdgcn_mfma_f32_16x16x32_f16(A[tt][0], B0, zz, 0, 0, 0);
      acc = __builtin_amdgcn_mfma_f32_16x16x32_f16(A[tt][1], B1, acc, 0, 0, 0);
      *reinterpret_cast<v4h*>(orow + tt * 16) = __builtin_convertvector(acc, v4h);
    }
  }
}

// ------------------------------------------------ phase 2: recurrent scan
// One wave = 16 sequences (MFMA columns). Lane owns seq s = lane&15.
// Per step: prefetch gi(t+1) + tok(t+2); 24 MFMA -> gh; in-lane gates;
// fp32 h update; pack f16; freeze (t < L) into hpk; LDS transpose -> B frag.

#define STEP(GC, GN)                                                          \
  {                                                                           \
    int i2_ = (t + 2 < L) ? (t + 2) : 0;                                      \
    int tk2_ = tokp[i2_];                                                     \
    {                                                                         \
      const _Float16* Pn_ = P16 + (size_t)tk1 * PROW + p * 4;                 \
      _Pragma("unroll")                                                       \
      for (int tt = 0; tt < 12; ++tt)                                         \
        GN[tt] = *reinterpret_cast<const v2u*>(Pn_ + tt * 16);                \
    }                                                                         \
    unsigned pw[4][2];                                                        \
    _Pragma("unroll")                                                         \
    for (int hf = 0; hf < 2; ++hf) {                                          \
      v4f ac[6];                                                              \
      _Pragma("unroll")                                                       \
      for (int g3 = 0; g3 < 3; ++g3) {                                        \
        _Pragma("unroll")                                                     \
        for (int tl = 0; tl < 2; ++tl) {                                      \
          const int tau = g3 * 4 + hf * 2 + tl;                               \
          v4f a0_ = __builtin_amdgcn_mfma_f32_16x16x32_f16(A[tau][0], Bf0,    \
                                                           zz, 0, 0, 0);      \
          ac[g3 * 2 + tl] = __builtin_amdgcn_mfma_f32_16x16x32_f16(           \
              A[tau][1], Bf1, a0_, 0, 0, 0);                                  \
        }                                                                     \
      }                                                                       \
      _Pragma("unroll")                                                       \
      for (int tl = 0; tl < 2; ++tl) {                                        \
        const int tau = hf * 2 + tl;                                          \
        float hn[4];                                                          \
        _Pragma("unroll")                                                     \
        for (int q = 0; q < 4; ++q) {                                         \
          const unsigned wr_ = GC[tau][q >> 1];                               \
          const unsigned wz_ = GC[4 + tau][q >> 1];                           \
          const unsigned wn_ = GC[8 + tau][q >> 1];                           \
          const float gir_ = (q & 1) ? hhi(wr_) : hlo(wr_);                   \
          const float giz_ = (q & 1) ? hhi(wz_) : hlo(wz_);                   \
          const float gin_ = (q & 1) ? hhi(wn_) : hlo(wn_);                   \
          float r_ = fsigmoid(ac[tl][q] + gir_);                              \
          float z_ = fsigmoid(ac[2 + tl][q] + giz_);                          \
          float n_ = ftanh(fmaf(r_, ac[4 + tl][q], gin_));                    \
          hn[q] = fmaf(z_, hv[tau][q] - n_, n_);                              \
          hv[tau][q] = hn[q];                                                 \
        }                                                                     \
        pw[tau][0] = pack_rne(hn[0], hn[1]);                                  \
        pw[tau][1] = pack_rne(hn[2], hn[3]);                                  \
      }                                                                       \
    }                                                                         \
    {                                                                         \
      const bool valid_ = (t < L);                                            \
      _Pragma("unroll")                                                       \
      for (int tau = 0; tau < 4; ++tau) {                                     \
        hpk[tau][0] = valid_ ? pw[tau][0] : hpk[tau][0];                      \
        hpk[tau][1] = valid_ ? pw[tau][1] : hpk[tau][1];                      \
        v2u wv_;                                                              \
        wv_[0] = pw[tau][0];                                                  \
        wv_[1] = pw[tau][1];                                                  \
        *reinterpret_cast<v2u*>(&hbuf[m * 80 + tau * 16 + p * 4]) = wv_;      \
      }                                                                       \
    }                                                                         \
    __builtin_amdgcn_wave_barrier();                                          \
    Bf0 = *reinterpret_cast<const v8h*>(&hbuf[m * 80 + p * 8]);               \
    Bf1 = *reinterpret_cast<const v8h*>(&hbuf[m * 80 + 32 + p * 8]);          \
    tk1 = tk2_;                                                               \
  }

__global__ __launch_bounds__(64) void gru_scan_mfma(
    const int* __restrict__ seq_token, const int* __restrict__ seq_pos,
    const _Float16* __restrict__ P16, const float* __restrict__ W_hh,
    float* __restrict__ out, int B) {
  // [16 seq rows][80 halves] = 160B row stride; writes 4-sweep floor,
  // b128 reads 8-sweep floor (even bank spread).
  __shared__ __align__(16) _Float16 hbuf[16 * 80];
  const int l = threadIdx.x;
  const int m = l & 15;
  const int p = l >> 4;
  const int b = blockIdx.x * 16 + m;
  const int bc = (b < B) ? b : 0;

  v8h A[12][2];
#pragma unroll
  for (int tt = 0; tt < 12; ++tt) {
    A[tt][0] = load_wfrag(W_hh, tt, 0, m, p);
    A[tt][1] = load_wfrag(W_hh, tt, 1, m, p);
  }

  int L;
  {
    int sp = seq_pos[bc];
    sp = sp < 1 ? 1 : (sp > T_SEQ ? T_SEQ : sp);
    L = (b < B) ? sp : 0;
  }
  int Lr = L;
#pragma unroll
  for (int off = 8; off; off >>= 1) {
    int o = __shfl_xor(Lr, off);
    Lr = Lr > o ? Lr : o;
  }
  const int Lmax = __builtin_amdgcn_readfirstlane(Lr);

  const int* tokp = seq_token + (size_t)bc * T_SEQ;

  v8h Bf0 = {0, 0, 0, 0, 0, 0, 0, 0};  // h = 0
  v8h Bf1 = {0, 0, 0, 0, 0, 0, 0, 0};
  float hv[4][4];       // fp32 running h, D layout: hv[tau][q] = h[16tau+4p+q]
  unsigned hpk[4][2];   // frozen packed h (output)
#pragma unroll
  for (int tau = 0; tau < 4; ++tau) {
    hv[tau][0] = hv[tau][1] = hv[tau][2] = hv[tau][3] = 0.f;
    hpk[tau][0] = hpk[tau][1] = 0u;
  }

  v2u gA[12], gB[12];
  int tk1;
  {
    const int tk0 = tokp[0];
    const _Float16* P0 = P16 + (size_t)tk0 * PROW + p * 4;
#pragma unroll
    for (int tt = 0; tt < 12; ++tt)
      gA[tt] = *reinterpret_cast<const v2u*>(P0 + tt * 16);
    tk1 = tokp[(1 < L) ? 1 : 0];
  }

  const v4f zz = {0.f, 0.f, 0.f, 0.f};
  int t = 0;
  while (t < Lmax) {
    STEP(gA, gB);
    ++t;
    if (t >= Lmax) break;
    STEP(gB, gA);
    ++t;
  }

  if (b < B) {
#pragma unroll
    for (int tau = 0; tau < 4; ++tau) {
#pragma unroll
      for (int qh = 0; qh < 2; ++qh) {
        float2 f;
        f.x = hlo(hpk[tau][qh]);
        f.y = hhi(hpk[tau][qh]);
        *reinterpret_cast<float2*>(out + (size_t)b * HD + tau * 16 + p * 4 +
                                   qh * 2) = f;
      }
    }
  }
}

extern "C" void kernel_launch(void* const* d_in, const int* in_sizes, int n_in,
                              void* d_out, int out_size, void* d_ws,
                              size_t ws_size, hipStream_t stream) {
  const int* seq_token = (const int*)d_in[0];   // [B, T] int32
  const int* seq_pos   = (const int*)d_in[1];   // [B] int32
  const float* emb     = (const float*)d_in[2]; // [V, H]
  const float* W_ih    = (const float*)d_in[3]; // [3H, H]
  const float* W_hh    = (const float*)d_in[4]; // [3H, H]
  float* out = (float*)d_out;                   // [B, H] fp32

  const int B = in_sizes[1];                    // 4096
  _Float16* P16 = (_Float16*)d_ws;              // 38.4 MB, plain [r|z|n] rows

  const int ntile = VOCAB / 16;                 // 6250
  gru_proj_mfma<<<(ntile + TPW - 1) / TPW, 64, 0, stream>>>(emb, W_ih, P16);
  gru_scan_mfma<<<(B + 15) / 16, 64, 0, stream>>>(seq_token, seq_pos, P16,
                                                  W_hh, out, B);
}